// Round 14
// baseline (187.084 us; speedup 1.0000x reference)
//
#include <hip/hip_runtime.h>
#include <hip/hip_bf16.h>
#include <math.h>

#define NEG 0.2f

typedef float f32x4 __attribute__((ext_vector_type(4)));
typedef short bf16x8 __attribute__((ext_vector_type(8)));

__device__ __forceinline__ float fsig(float x){ return 1.0f/(1.0f+__expf(-x)); }
__device__ __forceinline__ float ftanh(float x){ float e = __expf(2.0f*x); return 1.0f - 2.0f/(e+1.0f); }
__device__ __forceinline__ unsigned short f2bf(float v){
    __hip_bfloat16 b = __float2bfloat16(v);
    return *(unsigned short*)&b;
}
__device__ __forceinline__ bf16x8 pack8(float4 u, float4 v){
    bf16x8 r;
    r[0]=(short)f2bf(u.x); r[1]=(short)f2bf(u.y); r[2]=(short)f2bf(u.z); r[3]=(short)f2bf(u.w);
    r[4]=(short)f2bf(v.x); r[5]=(short)f2bf(v.y); r[6]=(short)f2bf(v.z); r[7]=(short)f2bf(v.w);
    return r;
}
__device__ __forceinline__ bf16x8 asbf(f32x4 v){ union{f32x4 f; bf16x8 h;} u; u.f=v; return u.h; }

// ---- merged: blocks 0-7 -> WPX pack, 8-71 -> WP2 pack (32-col groups), 72+ -> zero deg
// WP2 layout: group g (16 groups, 32 cols: gate*128 + g*8 + 0..7), frag q = ks*2+ct
//   ct0 covers [i-cols | f-cols], ct1 covers [g-cols | o-cols]  (split at lane bit 3)
__global__ __launch_bounds__(256) void k_pack(const float* __restrict__ W,
                                              const float* __restrict__ W_ih,
                                              const float* __restrict__ W_hh,
                                              unsigned short* __restrict__ WPX,
                                              unsigned short* __restrict__ WP2,
                                              int* __restrict__ deg, int n){
    const int bid = blockIdx.x;
    if(bid < 8){
        int f = bid*256 + threadIdx.x;
        int l = f&63, ct = (f>>6)&7, ks = f>>9;
        int k0 = ks*32 + (l>>4)*8;
        int col = ct*16 + (l&15);
        #pragma unroll
        for(int j=0;j<8;j++) WPX[(size_t)f*8+j] = f2bf(W[(size_t)(k0+j)*128 + col]);
    } else if(bid < 72){
        int f = (bid-8)*256 + threadIdx.x;      // 16384 thread-frags
        int l = f&63, q = (f>>6)&15, g = f>>10;
        int ks = q>>1, ct = q&1;
        int k0 = ks*32 + (l>>4)*8;
        int sub = l&15;
        int gate = ct*2 + (sub>>3);
        int col = gate*128 + g*8 + (sub&7);
        #pragma unroll
        for(int j=0;j<8;j++){
            int k = k0+j;
            float w = (k<128) ? W_ih[(size_t)col*128+k] : W_hh[(size_t)col*128+(k-128)];
            WP2[(size_t)f*8+j] = f2bf(w);
        }
    } else {
        int i = (bid-72)*256 + threadIdx.x;
        if(i < n) deg[i] = 0;
    }
}

// ---- fused: blocks < gemmBlk -> xs GEMM (B-from-L2, bf16 xsb + att dots);
//      blocks >= gemmBlk -> dst histogram (independent input)
__global__ __launch_bounds__(256,2) void k_gemm_hist(const float* __restrict__ x,
                                                     const unsigned short* __restrict__ WPX,
                                                     const float* __restrict__ att_s,
                                                     const float* __restrict__ att_d,
                                                     unsigned short* __restrict__ xsb,
                                                     float* __restrict__ a_src,
                                                     float* __restrict__ a_dst,
                                                     const int* __restrict__ ei,
                                                     int* __restrict__ deg,
                                                     int n, int ntiles, int gemmBlk,
                                                     int E, int EN){
    if((int)blockIdx.x >= gemmBlk){
        const int l = threadIdx.x & 63;
        unsigned long long m = __ballot(ei[2*l+1] != 0);
        const bool i64 = (m == 0ULL);
        int e = (blockIdx.x - gemmBlk)*256 + threadIdx.x;
        if(e>=EN) return;
        int dst = (e>=E) ? (e-E) : (i64 ? ei[2*(size_t)(E+e)] : ei[(size_t)E+e]);
        atomicAdd(&deg[dst], 1);
        return;
    }
    const int w = threadIdx.x>>6, l = threadIdx.x&63;
    const int wid = blockIdx.x*4 + w;
    const int nwaves = gemmBlk*4;
    bf16x8 B[32];
    #pragma unroll
    for(int f=0;f<32;f++) B[f] = *(const bf16x8*)(WPX + (size_t)(f*64 + l)*8);
    float asv[8], adv[8];
    #pragma unroll
    for(int ct=0;ct<8;ct++){
        asv[ct] = att_s[ct*16 + (l&15)];
        adv[ct] = att_d[ct*16 + (l&15)];
    }
    for(int rt = wid; rt < ntiles; rt += nwaves){
        int arow = rt*16 + (l&15); if(arow>=n) arow = n-1;
        const float* xr = x + (size_t)arow*128 + (l>>4)*8;
        bf16x8 A[4];
        #pragma unroll
        for(int ks=0;ks<4;ks++){
            float4 u = *(const float4*)(xr + ks*32);
            float4 v = *(const float4*)(xr + ks*32 + 4);
            A[ks] = pack8(u,v);
        }
        f32x4 acc[8];
        #pragma unroll
        for(int ct=0;ct<8;ct++) acc[ct] = (f32x4){0.f,0.f,0.f,0.f};
        #pragma unroll
        for(int ks=0;ks<4;ks++){
            #pragma unroll
            for(int ct=0;ct<8;ct++)
                acc[ct] = __builtin_amdgcn_mfma_f32_16x16x32_bf16(A[ks], B[ks*8+ct], acc[ct], 0,0,0);
        }
        #pragma unroll
        for(int reg=0;reg<4;reg++){
            int row = rt*16 + (l>>4)*4 + reg;
            float ps=0.f, pd=0.f;
            #pragma unroll
            for(int ct=0;ct<8;ct++){ ps += acc[ct][reg]*asv[ct]; pd += acc[ct][reg]*adv[ct]; }
            ps += __shfl_xor(ps,1); pd += __shfl_xor(pd,1);
            ps += __shfl_xor(ps,2); pd += __shfl_xor(pd,2);
            ps += __shfl_xor(ps,4); pd += __shfl_xor(pd,4);
            ps += __shfl_xor(ps,8); pd += __shfl_xor(pd,8);
            if((l&15)==0 && row<n){ a_src[row]=ps; a_dst[row]=pd; }
            if(row<n){
                #pragma unroll
                for(int ct=0;ct<8;ct++)
                    xsb[(size_t)row*128 + ct*16 + (l&15)] = f2bf(acc[ct][reg]);
            }
        }
    }
}

// ---- scan level 1: per-512-chunk sums
__global__ __launch_bounds__(256) void k_scan1(const int* __restrict__ deg,
                                               int* __restrict__ bsum, int n){
    __shared__ int ws[4];
    int b = blockIdx.x, t = threadIdx.x;
    int i = b*512 + t*2;
    int s = 0;
    if(i<n)   s += deg[i];
    if(i+1<n) s += deg[i+1];
    for(int off=32;off;off>>=1) s += __shfl_xor(s,off);
    if((t&63)==0) ws[t>>6]=s;
    __syncthreads();
    if(t==0) bsum[b]=ws[0]+ws[1]+ws[2]+ws[3];
}

// ---- scan level 3 (merged scan2): block computes its own bsum prefix, then
//      in-chunk exclusive scan -> rowptr, cursor
__global__ __launch_bounds__(256) void k_scan3(const int* __restrict__ deg,
                                               const int* __restrict__ bsum,
                                               int* __restrict__ rowptr,
                                               int* __restrict__ cursor,
                                               int n, int EN){
    __shared__ int wsum[4];
    __shared__ int boff;
    int b = blockIdx.x, t = threadIdx.x;
    if(t < 64){
        int a = 0;
        for(int i=t; i<b; i+=64) a += bsum[i];
        for(int off=32;off;off>>=1) a += __shfl_xor(a,off);
        if(t==0) boff = a;
    }
    int i = b*512 + t*2;
    int d0 = (i<n)?deg[i]:0, d1 = (i+1<n)?deg[i+1]:0;
    int s = d0+d1;
    int x = s;
    int lane = t&63, wv = t>>6;
    for(int dd=1; dd<64; dd<<=1){ int y=__shfl_up(x,dd); if(lane>=dd) x+=y; }
    if(lane==63) wsum[wv]=x;
    __syncthreads();
    int woff=0;
    for(int w=0;w<wv;w++) woff += wsum[w];
    int ex = boff + woff + x - s;
    if(i<n)   { rowptr[i]  =ex;    cursor[i]  =ex;    }
    if(i+1<n) { rowptr[i+1]=ex+d0; cursor[i+1]=ex+d0; }
    if(b==0 && t==0) rowptr[n]=EN;
}

// ---- fill CSR: csr_src[pos] = src for each edge grouped by dst
__global__ __launch_bounds__(256) void k_fill(const int* __restrict__ ei,
                                              int* __restrict__ cursor,
                                              int* __restrict__ csr_src, int E, int EN){
    const int l = threadIdx.x & 63;
    unsigned long long m = __ballot(ei[2*l+1] != 0);
    const bool i64 = (m == 0ULL);
    int e = blockIdx.x*256 + threadIdx.x;
    if(e>=EN) return;
    int src,dst;
    if(e>=E){ src=dst=e-E; }
    else if(i64){ src = ei[2*(size_t)e]; dst = ei[2*(size_t)(E+e)]; }
    else        { src = ei[(size_t)e];   dst = ei[(size_t)E+e]; }
    int pos = atomicAdd(&cursor[dst], 1);
    csr_src[pos] = src;
}

// ---- aggregate (bf16 gather, unroll-8) + GAT epilogue + h0 pack
__global__ __launch_bounds__(256) void k_agg3(const int* __restrict__ rowptr,
                                              const int* __restrict__ csr_src,
                                              const float* __restrict__ a_src,
                                              const float* __restrict__ a_dst,
                                              const unsigned int* __restrict__ xsb32,
                                              const float* __restrict__ bg,
                                              const float* __restrict__ h0,
                                              unsigned short* __restrict__ xh, int n){
    const int wv = threadIdx.x>>6, l = threadIdx.x&63;
    const int dst = blockIdx.x*4 + wv;
    if(dst>=n) return;
    const int beg = rowptr[dst], end = rowptr[dst+1];
    const float ad = a_dst[dst];
    float ax=0.f, ay=0.f, psum=0.f;
    int j = beg;
    for(; j+8<=end; j+=8){
        int s0=csr_src[j],   s1=csr_src[j+1], s2=csr_src[j+2], s3=csr_src[j+3];
        int s4=csr_src[j+4], s5=csr_src[j+5], s6=csr_src[j+6], s7=csr_src[j+7];
        float e0=a_src[s0]+ad, e1=a_src[s1]+ad, e2=a_src[s2]+ad, e3=a_src[s3]+ad;
        float e4=a_src[s4]+ad, e5=a_src[s5]+ad, e6=a_src[s6]+ad, e7=a_src[s7]+ad;
        unsigned k0=xsb32[(size_t)s0*64+l], k1=xsb32[(size_t)s1*64+l];
        unsigned k2=xsb32[(size_t)s2*64+l], k3=xsb32[(size_t)s3*64+l];
        unsigned k4=xsb32[(size_t)s4*64+l], k5=xsb32[(size_t)s5*64+l];
        unsigned k6=xsb32[(size_t)s6*64+l], k7=xsb32[(size_t)s7*64+l];
        e0=e0>=0.f?e0:NEG*e0; e1=e1>=0.f?e1:NEG*e1; e2=e2>=0.f?e2:NEG*e2; e3=e3>=0.f?e3:NEG*e3;
        e4=e4>=0.f?e4:NEG*e4; e5=e5>=0.f?e5:NEG*e5; e6=e6>=0.f?e6:NEG*e6; e7=e7>=0.f?e7:NEG*e7;
        float p0=__expf(e0), p1=__expf(e1), p2=__expf(e2), p3=__expf(e3);
        float p4=__expf(e4), p5=__expf(e5), p6=__expf(e6), p7=__expf(e7);
        psum += (p0+p1+p2+p3)+(p4+p5+p6+p7);
        ax += p0*__uint_as_float(k0<<16) + p1*__uint_as_float(k1<<16)
            + p2*__uint_as_float(k2<<16) + p3*__uint_as_float(k3<<16)
            + p4*__uint_as_float(k4<<16) + p5*__uint_as_float(k5<<16)
            + p6*__uint_as_float(k6<<16) + p7*__uint_as_float(k7<<16);
        ay += p0*__uint_as_float(k0&0xffff0000u) + p1*__uint_as_float(k1&0xffff0000u)
            + p2*__uint_as_float(k2&0xffff0000u) + p3*__uint_as_float(k3&0xffff0000u)
            + p4*__uint_as_float(k4&0xffff0000u) + p5*__uint_as_float(k5&0xffff0000u)
            + p6*__uint_as_float(k6&0xffff0000u) + p7*__uint_as_float(k7&0xffff0000u);
    }
    for(; j<end; ++j){
        int s = csr_src[j];
        float sv = a_src[s]+ad;
        sv = sv>=0.f ? sv : NEG*sv;
        float p = __expf(sv);
        psum += p;
        unsigned pk = xsb32[(size_t)s*64 + l];
        ax += p*__uint_as_float(pk<<16);
        ay += p*__uint_as_float(pk & 0xffff0000u);
    }
    const float inv = 1.0f/(psum + 1e-16f);
    float t0 = ftanh(ax*inv + bg[2*l]);
    float t1 = ftanh(ay*inv + bg[2*l+1]);
    unsigned int pk = (unsigned)f2bf(t0) | ((unsigned)f2bf(t1)<<16);
    unsigned int* xr = (unsigned int*)(xh + (size_t)dst*256);
    xr[l] = pk;
    float2 hv = *(const float2*)(h0 + (size_t)dst*128 + 2*l);
    xr[64 + l] = (unsigned)f2bf(hv.x) | ((unsigned)f2bf(hv.y)<<16);
}

// ---- LSTM via MFMA: 32-col groups -> B = 16 frags = 64 AGPR, 4 waves/SIMD.
//      Gate quadruple split across lane-halves; fixed via shfl_xor(8) in epilogue.
__global__ __launch_bounds__(256,4) void k_lstm12(const unsigned short* __restrict__ xh,
                                                  const unsigned short* __restrict__ WP2,
                                                  const float* __restrict__ c0,
                                                  float* __restrict__ out,
                                                  int n, int ntiles, int wstride){
    const int t = threadIdx.x;
    const int w = t>>6, l = t&63;
    const int wid = blockIdx.x*4 + w;
    const int g = wid & 15, wgi = wid >> 4;
    const unsigned short* wp = WP2 + (size_t)g*8192;
    f32x4 B[16];
    #pragma unroll
    for(int q=0;q<16;q++) B[q] = *(const f32x4*)(wp + (size_t)(q*64 + l)*8);
    #pragma unroll
    for(int q=0;q<16;q++) asm volatile("" : "+v"(B[q]));   // pin: forbid remat/reload
    const size_t nn = (size_t)n*128;
    const bool lower = ((l&15) < 8);
    const int col = g*8 + (l&7);               // output col for lower lanes
    for(int rt = wgi; rt < ntiles; rt += wstride){
        int arow = rt*16 + (l&15); if(arow>=n) arow=n-1;
        const unsigned short* ar = xh + (size_t)arow*256 + (l>>4)*8;
        bf16x8 A[8];
        #pragma unroll
        for(int ks=0;ks<8;ks++) A[ks] = *(const bf16x8*)(ar + ks*32);
        const int rbase = rt*16 + (l>>4)*4;
        float cc[4];
        if(lower){
            #pragma unroll
            for(int r=0;r<4;r++){ int rr=rbase+r; if(rr>=n) rr=n-1; cc[r]=c0[(size_t)rr*128+col]; }
        }
        f32x4 acc0 = (f32x4){0.f,0.f,0.f,0.f};
        f32x4 acc1 = (f32x4){0.f,0.f,0.f,0.f};
        #pragma unroll
        for(int ks=0;ks<8;ks++){
            acc0 = __builtin_amdgcn_mfma_f32_16x16x32_bf16(A[ks], asbf(B[ks*2  ]), acc0, 0,0,0);
            acc1 = __builtin_amdgcn_mfma_f32_16x16x32_bf16(A[ks], asbf(B[ks*2+1]), acc1, 0,0,0);
        }
        #pragma unroll
        for(int reg=0;reg<4;reg++){
            int row = rbase + reg;
            float v0 = acc0[reg];              // lower: gi   upper: gf
            float v1 = acc1[reg];              // lower: gg   upper: go
            float p0 = __shfl_xor(v0, 8);      // lower receives gf
            float p1 = __shfl_xor(v1, 8);      // lower receives go
            if(lower && row<n){
                float c1v = fsig(p0)*cc[reg] + fsig(v0)*ftanh(v1);
                float h1v = fsig(p1)*ftanh(c1v);
                out[(size_t)row*128+col]        = h1v;
                out[nn + (size_t)row*128+col]   = h1v;
                out[2*nn + (size_t)row*128+col] = c1v;
            }
        }
    }
}

extern "C" void kernel_launch(void* const* d_in, const int* in_sizes, int n_in,
                              void* d_out, int out_size, void* d_ws, size_t ws_size,
                              hipStream_t stream) {
    const float* x      = (const float*)d_in[0];
    const int*   ei     = (const int*)  d_in[1];
    const float* h      = (const float*)d_in[2];
    const float* c      = (const float*)d_in[3];
    const float* W      = (const float*)d_in[4];
    const float* atts   = (const float*)d_in[5];
    const float* attd   = (const float*)d_in[6];
    const float* bias   = (const float*)d_in[7];
    const float* W_ih   = (const float*)d_in[8];
    const float* W_hh   = (const float*)d_in[9];
    float* out = (float*)d_out;

    const int n  = in_sizes[0]/128;
    const int E  = in_sizes[1]/2;
    const int EN = E + n;
    const int NB = (n + 511)/512;
    const int ntiles = (n + 15)/16;
    const int n2 = ntiles*16;
    const int histBlk = (EN + 255)/256;
    const int degBlk  = (n + 255)/256;

    unsigned short* xsb = (unsigned short*)d_ws;          // n*128 bf16
    unsigned short* xh  = xsb + (size_t)n*128;            // n2*256 bf16
    unsigned short* WP2 = xh + (size_t)n2*256;            // 131072 bf16
    unsigned short* WPX = WP2 + 131072;                   // 16384 bf16
    float* a_src = (float*)(WPX + 16384);                 // n
    float* a_dst = a_src + n;                             // n
    int*   deg    = (int*)(a_dst + n);                    // n
    int*   rowptr = deg + n;                              // n+1
    int*   cursor = rowptr + n + 1;                       // n
    int*   bsum   = cursor + n;                           // 128
    int*   csr_src= bsum + 128;                           // EN

    k_pack<<<72+degBlk,256,0,stream>>>(W, W_ih, W_hh, WPX, WP2, deg, n);
    k_gemm_hist<<<1024+histBlk,256,0,stream>>>(x, WPX, atts, attd, xsb, a_src, a_dst,
                                               ei, deg, n, ntiles, 1024, E, EN);
    k_scan1<<<NB,256,0,stream>>>(deg,bsum,n);
    k_scan3<<<NB,256,0,stream>>>(deg,bsum,rowptr,cursor,n,EN);
    k_fill<<<histBlk,256,0,stream>>>(ei,cursor,csr_src,E,EN);
    k_agg3<<<(n+3)/4,256,0,stream>>>(rowptr,csr_src,a_src,a_dst,(const unsigned int*)xsb,bias,h,xh,n);
    k_lstm12<<<1024,256,0,stream>>>(xh, WP2, c, out, n, ntiles, 256);
}

// Round 15
// 162.218 us; speedup vs baseline: 1.1533x; 1.1533x over previous
//
#include <hip/hip_runtime.h>
#include <hip/hip_bf16.h>
#include <math.h>

#define NEG 0.2f

typedef float f32x4 __attribute__((ext_vector_type(4)));
typedef short bf16x8 __attribute__((ext_vector_type(8)));

__device__ __forceinline__ float fsig(float x){ return 1.0f/(1.0f+__expf(-x)); }
__device__ __forceinline__ float ftanh(float x){ float e = __expf(2.0f*x); return 1.0f - 2.0f/(e+1.0f); }
__device__ __forceinline__ unsigned short f2bf(float v){
    __hip_bfloat16 b = __float2bfloat16(v);
    return *(unsigned short*)&b;
}
__device__ __forceinline__ bf16x8 pack8(float4 u, float4 v){
    bf16x8 r;
    r[0]=(short)f2bf(u.x); r[1]=(short)f2bf(u.y); r[2]=(short)f2bf(u.z); r[3]=(short)f2bf(u.w);
    r[4]=(short)f2bf(v.x); r[5]=(short)f2bf(v.y); r[6]=(short)f2bf(v.z); r[7]=(short)f2bf(v.w);
    return r;
}
__device__ __forceinline__ bf16x8 asbf(f32x4 v){ union{f32x4 f; bf16x8 h;} u; u.f=v; return u.h; }

// ---- merged: blocks 0-7 -> WPX pack, 8-71 -> WP2 pack (64-col groups), 72+ -> zero deg
__global__ __launch_bounds__(256) void k_pack(const float* __restrict__ W,
                                              const float* __restrict__ W_ih,
                                              const float* __restrict__ W_hh,
                                              unsigned short* __restrict__ WPX,
                                              unsigned short* __restrict__ WP2,
                                              int* __restrict__ deg, int n){
    const int bid = blockIdx.x;
    if(bid < 8){
        int f = bid*256 + threadIdx.x;
        int l = f&63, ct = (f>>6)&7, ks = f>>9;
        int k0 = ks*32 + (l>>4)*8;
        int col = ct*16 + (l&15);
        #pragma unroll
        for(int j=0;j<8;j++) WPX[(size_t)f*8+j] = f2bf(W[(size_t)(k0+j)*128 + col]);
    } else if(bid < 72){
        int f = (bid-8)*256 + threadIdx.x;
        int l = f&63, ct = (f>>6)&3, ks = (f>>8)&7, g = f>>11;
        int k0 = ks*32 + (l>>4)*8;
        int col = ct*128 + g*16 + (l&15);
        #pragma unroll
        for(int j=0;j<8;j++){
            int k = k0+j;
            float w = (k<128) ? W_ih[(size_t)col*128+k] : W_hh[(size_t)col*128+(k-128)];
            WP2[(size_t)f*8+j] = f2bf(w);
        }
    } else {
        int i = (bid-72)*256 + threadIdx.x;
        if(i < n) deg[i] = 0;
    }
}

// ---- fused: blocks < gemmBlk -> xs GEMM (B-from-L2, bf16 xsb + att dots);
//      blocks >= gemmBlk -> dst histogram (independent input)
__global__ __launch_bounds__(256,2) void k_gemm_hist(const float* __restrict__ x,
                                                     const unsigned short* __restrict__ WPX,
                                                     const float* __restrict__ att_s,
                                                     const float* __restrict__ att_d,
                                                     unsigned short* __restrict__ xsb,
                                                     float* __restrict__ a_src,
                                                     float* __restrict__ a_dst,
                                                     const int* __restrict__ ei,
                                                     int* __restrict__ deg,
                                                     int n, int ntiles, int gemmBlk,
                                                     int E, int EN){
    if((int)blockIdx.x >= gemmBlk){
        const int l = threadIdx.x & 63;
        unsigned long long m = __ballot(ei[2*l+1] != 0);
        const bool i64 = (m == 0ULL);
        int e = (blockIdx.x - gemmBlk)*256 + threadIdx.x;
        if(e>=EN) return;
        int dst = (e>=E) ? (e-E) : (i64 ? ei[2*(size_t)(E+e)] : ei[(size_t)E+e]);
        atomicAdd(&deg[dst], 1);
        return;
    }
    const int w = threadIdx.x>>6, l = threadIdx.x&63;
    const int wid = blockIdx.x*4 + w;
    const int nwaves = gemmBlk*4;
    bf16x8 B[32];
    #pragma unroll
    for(int f=0;f<32;f++) B[f] = *(const bf16x8*)(WPX + (size_t)(f*64 + l)*8);
    float asv[8], adv[8];
    #pragma unroll
    for(int ct=0;ct<8;ct++){
        asv[ct] = att_s[ct*16 + (l&15)];
        adv[ct] = att_d[ct*16 + (l&15)];
    }
    for(int rt = wid; rt < ntiles; rt += nwaves){
        int arow = rt*16 + (l&15); if(arow>=n) arow = n-1;
        const float* xr = x + (size_t)arow*128 + (l>>4)*8;
        bf16x8 A[4];
        #pragma unroll
        for(int ks=0;ks<4;ks++){
            float4 u = *(const float4*)(xr + ks*32);
            float4 v = *(const float4*)(xr + ks*32 + 4);
            A[ks] = pack8(u,v);
        }
        f32x4 acc[8];
        #pragma unroll
        for(int ct=0;ct<8;ct++) acc[ct] = (f32x4){0.f,0.f,0.f,0.f};
        #pragma unroll
        for(int ks=0;ks<4;ks++){
            #pragma unroll
            for(int ct=0;ct<8;ct++)
                acc[ct] = __builtin_amdgcn_mfma_f32_16x16x32_bf16(A[ks], B[ks*8+ct], acc[ct], 0,0,0);
        }
        #pragma unroll
        for(int reg=0;reg<4;reg++){
            int row = rt*16 + (l>>4)*4 + reg;
            float ps=0.f, pd=0.f;
            #pragma unroll
            for(int ct=0;ct<8;ct++){ ps += acc[ct][reg]*asv[ct]; pd += acc[ct][reg]*adv[ct]; }
            ps += __shfl_xor(ps,1); pd += __shfl_xor(pd,1);
            ps += __shfl_xor(ps,2); pd += __shfl_xor(pd,2);
            ps += __shfl_xor(ps,4); pd += __shfl_xor(pd,4);
            ps += __shfl_xor(ps,8); pd += __shfl_xor(pd,8);
            if((l&15)==0 && row<n){ a_src[row]=ps; a_dst[row]=pd; }
            if(row<n){
                #pragma unroll
                for(int ct=0;ct<8;ct++)
                    xsb[(size_t)row*128 + ct*16 + (l&15)] = f2bf(acc[ct][reg]);
            }
        }
    }
}

// ---- scan level 1: per-512-chunk sums
__global__ __launch_bounds__(256) void k_scan1(const int* __restrict__ deg,
                                               int* __restrict__ bsum, int n){
    __shared__ int ws[4];
    int b = blockIdx.x, t = threadIdx.x;
    int i = b*512 + t*2;
    int s = 0;
    if(i<n)   s += deg[i];
    if(i+1<n) s += deg[i+1];
    for(int off=32;off;off>>=1) s += __shfl_xor(s,off);
    if((t&63)==0) ws[t>>6]=s;
    __syncthreads();
    if(t==0) bsum[b]=ws[0]+ws[1]+ws[2]+ws[3];
}

// ---- scan level 3 (merged scan2): block computes its own bsum prefix, then
//      in-chunk exclusive scan -> rowptr, cursor
__global__ __launch_bounds__(256) void k_scan3(const int* __restrict__ deg,
                                               const int* __restrict__ bsum,
                                               int* __restrict__ rowptr,
                                               int* __restrict__ cursor,
                                               int n, int EN){
    __shared__ int wsum[4];
    __shared__ int boff;
    int b = blockIdx.x, t = threadIdx.x;
    if(t < 64){
        int a = 0;
        for(int i=t; i<b; i+=64) a += bsum[i];
        for(int off=32;off;off>>=1) a += __shfl_xor(a,off);
        if(t==0) boff = a;
    }
    int i = b*512 + t*2;
    int d0 = (i<n)?deg[i]:0, d1 = (i+1<n)?deg[i+1]:0;
    int s = d0+d1;
    int x = s;
    int lane = t&63, wv = t>>6;
    for(int dd=1; dd<64; dd<<=1){ int y=__shfl_up(x,dd); if(lane>=dd) x+=y; }
    if(lane==63) wsum[wv]=x;
    __syncthreads();
    int woff=0;
    for(int w=0;w<wv;w++) woff += wsum[w];
    int ex = boff + woff + x - s;
    if(i<n)   { rowptr[i]  =ex;    cursor[i]  =ex;    }
    if(i+1<n) { rowptr[i+1]=ex+d0; cursor[i+1]=ex+d0; }
    if(b==0 && t==0) rowptr[n]=EN;
}

// ---- fill CSR: csr_src[pos] = src for each edge grouped by dst
__global__ __launch_bounds__(256) void k_fill(const int* __restrict__ ei,
                                              int* __restrict__ cursor,
                                              int* __restrict__ csr_src, int E, int EN){
    const int l = threadIdx.x & 63;
    unsigned long long m = __ballot(ei[2*l+1] != 0);
    const bool i64 = (m == 0ULL);
    int e = blockIdx.x*256 + threadIdx.x;
    if(e>=EN) return;
    int src,dst;
    if(e>=E){ src=dst=e-E; }
    else if(i64){ src = ei[2*(size_t)e]; dst = ei[2*(size_t)(E+e)]; }
    else        { src = ei[(size_t)e];   dst = ei[(size_t)E+e]; }
    int pos = atomicAdd(&cursor[dst], 1);
    csr_src[pos] = src;
}

// ---- aggregate (bf16 gather, unroll-8) + GAT epilogue + h0 pack
__global__ __launch_bounds__(256) void k_agg3(const int* __restrict__ rowptr,
                                              const int* __restrict__ csr_src,
                                              const float* __restrict__ a_src,
                                              const float* __restrict__ a_dst,
                                              const unsigned int* __restrict__ xsb32,
                                              const float* __restrict__ bg,
                                              const float* __restrict__ h0,
                                              unsigned short* __restrict__ xh, int n){
    const int wv = threadIdx.x>>6, l = threadIdx.x&63;
    const int dst = blockIdx.x*4 + wv;
    if(dst>=n) return;
    const int beg = rowptr[dst], end = rowptr[dst+1];
    const float ad = a_dst[dst];
    float ax=0.f, ay=0.f, psum=0.f;
    int j = beg;
    for(; j+8<=end; j+=8){
        int s0=csr_src[j],   s1=csr_src[j+1], s2=csr_src[j+2], s3=csr_src[j+3];
        int s4=csr_src[j+4], s5=csr_src[j+5], s6=csr_src[j+6], s7=csr_src[j+7];
        float e0=a_src[s0]+ad, e1=a_src[s1]+ad, e2=a_src[s2]+ad, e3=a_src[s3]+ad;
        float e4=a_src[s4]+ad, e5=a_src[s5]+ad, e6=a_src[s6]+ad, e7=a_src[s7]+ad;
        unsigned k0=xsb32[(size_t)s0*64+l], k1=xsb32[(size_t)s1*64+l];
        unsigned k2=xsb32[(size_t)s2*64+l], k3=xsb32[(size_t)s3*64+l];
        unsigned k4=xsb32[(size_t)s4*64+l], k5=xsb32[(size_t)s5*64+l];
        unsigned k6=xsb32[(size_t)s6*64+l], k7=xsb32[(size_t)s7*64+l];
        e0=e0>=0.f?e0:NEG*e0; e1=e1>=0.f?e1:NEG*e1; e2=e2>=0.f?e2:NEG*e2; e3=e3>=0.f?e3:NEG*e3;
        e4=e4>=0.f?e4:NEG*e4; e5=e5>=0.f?e5:NEG*e5; e6=e6>=0.f?e6:NEG*e6; e7=e7>=0.f?e7:NEG*e7;
        float p0=__expf(e0), p1=__expf(e1), p2=__expf(e2), p3=__expf(e3);
        float p4=__expf(e4), p5=__expf(e5), p6=__expf(e6), p7=__expf(e7);
        psum += (p0+p1+p2+p3)+(p4+p5+p6+p7);
        ax += p0*__uint_as_float(k0<<16) + p1*__uint_as_float(k1<<16)
            + p2*__uint_as_float(k2<<16) + p3*__uint_as_float(k3<<16)
            + p4*__uint_as_float(k4<<16) + p5*__uint_as_float(k5<<16)
            + p6*__uint_as_float(k6<<16) + p7*__uint_as_float(k7<<16);
        ay += p0*__uint_as_float(k0&0xffff0000u) + p1*__uint_as_float(k1&0xffff0000u)
            + p2*__uint_as_float(k2&0xffff0000u) + p3*__uint_as_float(k3&0xffff0000u)
            + p4*__uint_as_float(k4&0xffff0000u) + p5*__uint_as_float(k5&0xffff0000u)
            + p6*__uint_as_float(k6&0xffff0000u) + p7*__uint_as_float(k7&0xffff0000u);
    }
    for(; j<end; ++j){
        int s = csr_src[j];
        float sv = a_src[s]+ad;
        sv = sv>=0.f ? sv : NEG*sv;
        float p = __expf(sv);
        psum += p;
        unsigned pk = xsb32[(size_t)s*64 + l];
        ax += p*__uint_as_float(pk<<16);
        ay += p*__uint_as_float(pk & 0xffff0000u);
    }
    const float inv = 1.0f/(psum + 1e-16f);
    float t0 = ftanh(ax*inv + bg[2*l]);
    float t1 = ftanh(ay*inv + bg[2*l+1]);
    unsigned int pk = (unsigned)f2bf(t0) | ((unsigned)f2bf(t1)<<16);
    unsigned int* xr = (unsigned int*)(xh + (size_t)dst*256);
    xr[l] = pk;
    float2 hv = *(const float2*)(h0 + (size_t)dst*128 + 2*l);
    xr[64 + l] = (unsigned)f2bf(hv.x) | ((unsigned)f2bf(hv.y)<<16);
}

// ---- LSTM via MFMA: 8-wave block = all 8 col-groups of a contiguous tile run.
//      B pinned resident (AGPR), A+c0 prefetch, full output rows per block.
__global__ __launch_bounds__(512,1) void k_lstm13(const unsigned short* __restrict__ xh,
                                                  const unsigned short* __restrict__ WP2,
                                                  const float* __restrict__ c0,
                                                  float* __restrict__ out,
                                                  int n, int ntiles, int tpb){
    const int t = threadIdx.x;
    const int w = t>>6, l = t&63;
    const int g = w;                            // wave = col-group; block = full row
    const unsigned short* wp = WP2 + (size_t)g*16384;
    f32x4 B[32];
    #pragma unroll
    for(int f=0;f<32;f++) B[f] = *(const f32x4*)(wp + (size_t)(f*64 + l)*8);
    #pragma unroll
    for(int f=0;f<32;f++) asm volatile("" : "+v"(B[f]));   // pin: forbid remat/reload
    const size_t nn = (size_t)n*128;
    const int col = g*16 + (l&15);
    int rt = blockIdx.x*tpb;
    const int rtEnd = min(rt + tpb, ntiles);
    if(rt >= rtEnd) return;
    bf16x8 A[8]; float cc[4];
    {
        int arow = rt*16 + (l&15); if(arow>=n) arow=n-1;
        const unsigned short* ar = xh + (size_t)arow*256 + (l>>4)*8;
        #pragma unroll
        for(int ks=0;ks<8;ks++) A[ks] = *(const bf16x8*)(ar + ks*32);
        int rbase = rt*16 + (l>>4)*4;
        #pragma unroll
        for(int r=0;r<4;r++){ int rr=rbase+r; if(rr>=n) rr=n-1; cc[r]=c0[(size_t)rr*128+col]; }
    }
    while(rt < rtEnd){
        const int rtn = rt + 1;
        bf16x8 A2[8]; float cc2[4];
        if(rtn < rtEnd){
            int arow = rtn*16 + (l&15); if(arow>=n) arow=n-1;
            const unsigned short* ar = xh + (size_t)arow*256 + (l>>4)*8;
            #pragma unroll
            for(int ks=0;ks<8;ks++) A2[ks] = *(const bf16x8*)(ar + ks*32);
            int rbase = rtn*16 + (l>>4)*4;
            #pragma unroll
            for(int r=0;r<4;r++){ int rr=rbase+r; if(rr>=n) rr=n-1; cc2[r]=c0[(size_t)rr*128+col]; }
        }
        f32x4 acc[4];
        #pragma unroll
        for(int ct=0;ct<4;ct++) acc[ct] = (f32x4){0.f,0.f,0.f,0.f};
        #pragma unroll
        for(int ks=0;ks<8;ks++){
            #pragma unroll
            for(int ct=0;ct<4;ct++)
                acc[ct] = __builtin_amdgcn_mfma_f32_16x16x32_bf16(A[ks], asbf(B[ks*4+ct]), acc[ct], 0,0,0);
        }
        #pragma unroll
        for(int reg=0;reg<4;reg++){
            int row = rt*16 + (l>>4)*4 + reg;
            if(row>=n) continue;
            float gi=acc[0][reg], gf=acc[1][reg], gg=acc[2][reg], go=acc[3][reg];
            float c1v = fsig(gf)*cc[reg] + fsig(gi)*ftanh(gg);
            float h1v = fsig(go)*ftanh(c1v);
            out[(size_t)row*128+col]        = h1v;
            out[nn + (size_t)row*128+col]   = h1v;
            out[2*nn + (size_t)row*128+col] = c1v;
        }
        rt = rtn;
        if(rt < rtEnd){
            #pragma unroll
            for(int ks=0;ks<8;ks++) A[ks] = A2[ks];
            #pragma unroll
            for(int r=0;r<4;r++) cc[r] = cc2[r];
        }
    }
}

extern "C" void kernel_launch(void* const* d_in, const int* in_sizes, int n_in,
                              void* d_out, int out_size, void* d_ws, size_t ws_size,
                              hipStream_t stream) {
    const float* x      = (const float*)d_in[0];
    const int*   ei     = (const int*)  d_in[1];
    const float* h      = (const float*)d_in[2];
    const float* c      = (const float*)d_in[3];
    const float* W      = (const float*)d_in[4];
    const float* atts   = (const float*)d_in[5];
    const float* attd   = (const float*)d_in[6];
    const float* bias   = (const float*)d_in[7];
    const float* W_ih   = (const float*)d_in[8];
    const float* W_hh   = (const float*)d_in[9];
    float* out = (float*)d_out;

    const int n  = in_sizes[0]/128;
    const int E  = in_sizes[1]/2;
    const int EN = E + n;
    const int NB = (n + 511)/512;
    const int ntiles = (n + 15)/16;
    const int n2 = ntiles*16;
    const int histBlk = (EN + 255)/256;
    const int degBlk  = (n + 255)/256;
    const int tpb = (ntiles + 255)/256;                   // tiles per 8-wave block
    const int lstmBlk = (ntiles + tpb - 1)/tpb;           // <=256 resident blocks

    unsigned short* xsb = (unsigned short*)d_ws;          // n*128 bf16
    unsigned short* xh  = xsb + (size_t)n*128;            // n2*256 bf16
    unsigned short* WP2 = xh + (size_t)n2*256;            // 131072 bf16
    unsigned short* WPX = WP2 + 131072;                   // 16384 bf16
    float* a_src = (float*)(WPX + 16384);                 // n
    float* a_dst = a_src + n;                             // n
    int*   deg    = (int*)(a_dst + n);                    // n
    int*   rowptr = deg + n;                              // n+1
    int*   cursor = rowptr + n + 1;                       // n
    int*   bsum   = cursor + n;                           // 128
    int*   csr_src= bsum + 128;                           // EN

    k_pack<<<72+degBlk,256,0,stream>>>(W, W_ih, W_hh, WPX, WP2, deg, n);
    k_gemm_hist<<<1024+histBlk,256,0,stream>>>(x, WPX, atts, attd, xsb, a_src, a_dst,
                                               ei, deg, n, ntiles, 1024, E, EN);
    k_scan1<<<NB,256,0,stream>>>(deg,bsum,n);
    k_scan3<<<NB,256,0,stream>>>(deg,bsum,rowptr,cursor,n,EN);
    k_fill<<<histBlk,256,0,stream>>>(ei,cursor,csr_src,E,EN);
    k_agg3<<<(n+3)/4,256,0,stream>>>(rowptr,csr_src,a_src,a_dst,(const unsigned int*)xsb,bias,h,xh,n);
    k_lstm13<<<lstmBlk,512,0,stream>>>(xh, WP2, c, out, n, ntiles, tpb);
}